// Round 3
// baseline (1305.535 us; speedup 1.0000x reference)
//
#include <hip/hip_runtime.h>
#include <math.h>

// RMAC for x[64][512][32][32] fp32, L=3, OVR=0.4, EPS=1e-6.
// Regions for H=W=32 (14 distinct, global counted twice):
//   r0 : rows[0,32) cols[0,32)                       (weight 2)
//   r1-4 : rows{[0,21),[11,32)} x cols{[0,21),[11,32)}
//   r5-13: rows{[0,16),[8,24),[16,32)} x cols{[0,16),[8,24),[16,32)}
//
// v4: single fused kernel (v3 + race fix). Wave-per-tile register-only pooling
// (verified in v2), packed [tile][16] vt records, last-block-per-b norm tail.
// RACE FIX vs v3: v3 did stores -> fence -> atomicAdd -> syncthreads; thread 0
// could count the block done before waves 1-3 stored their records.
// Correct order (CUDA threadFenceReduction pattern):
//   stores -> __threadfence() -> __syncthreads() -> t0 atomicAdd
//   -> __syncthreads() -> isLast ? acquire fence + norm tail.

#define B_ 64
#define C_ 512
#define BC 32768            // B_*C_

template<int IMM>
__device__ __forceinline__ float max_swz(float x) {
    int y = __builtin_amdgcn_ds_swizzle(__float_as_int(x), IMM);
    return fmaxf(x, __int_as_float(y));
}
template<int IMM>
__device__ __forceinline__ float swz(float x) {
    return __int_as_float(__builtin_amdgcn_ds_swizzle(__float_as_int(x), IMM));
}
__device__ __forceinline__ float max_x32(float x) {
#if __has_builtin(__builtin_amdgcn_permlane32_swap)
    auto r = __builtin_amdgcn_permlane32_swap(__float_as_int(x), __float_as_int(x),
                                              false, false);
    return fmaxf(__int_as_float((int)r[0]), __int_as_float((int)r[1]));
#else
    return fmaxf(x, __shfl_xor(x, 32, 64));
#endif
}

#define SWZ_X1  0x041F
#define SWZ_X2  0x081F
#define SWZ_X4  0x101F
#define SWZ_X8  0x201F
#define SWZ_X16 0x401F

__global__ __launch_bounds__(256) void rmac_fused_kernel(const float* __restrict__ x,
                                                         float* __restrict__ vt,
                                                         int* __restrict__ cnt,
                                                         float* __restrict__ out) {
    const int lane = threadIdx.x & 63;
    const int tile = (blockIdx.x << 2) | (threadIdx.x >> 6);   // = b*C_ + c
    const float4* __restrict__ xv = (const float4*)(x + ((long long)tile << 10));

    // coalesced: 4 x (64 lanes x 16B) = the whole 4KB tile
    const float4 v0 = xv[lane];          // row h0,     cols 4g..4g+3
    const float4 v1 = xv[lane + 64];     // row h0+8
    const float4 v2 = xv[lane + 128];    // row h0+16
    const float4 v3 = xv[lane + 192];    // row h0+24

    const int h0 = lane >> 3;
    const int g  = lane & 7;
    const float NEG = -INFINITY;

    // per-row max over this lane's 4 columns
    const float gm0 = fmaxf(fmaxf(v0.x, v0.y), fmaxf(v0.z, v0.w));
    const float gm1 = fmaxf(fmaxf(v1.x, v1.y), fmaxf(v1.z, v1.w));
    const float gm2 = fmaxf(fmaxf(v2.x, v2.y), fmaxf(v2.z, v2.w));
    const float gm3 = fmaxf(fmaxf(v3.x, v3.y), fmaxf(v3.z, v3.w));

    // row-range maxes over the lane's rows {h0, h0+8, h0+16, h0+24}
    float a3 = fmaxf(gm0, gm1);                        // rows [0,16)
    float a5 = fmaxf(gm2, gm3);                        // rows [16,32)
    float a0 = fmaxf(a3, a5);                          // rows [0,32)
    float a4 = fmaxf(gm1, gm2);                        // rows [8,24)
    float a1 = fmaxf(a3, (h0 < 5)  ? gm2 : NEG);       // rows [0,21):  h0+16<21
    float a2 = fmaxf(a5, (h0 >= 3) ? gm1 : NEG);       // rows [11,32): h0+8>=11

    // special single columns: col 11 = (g2, j3); col 20 = (g5, j0)
    const bool g2sel = (g == 2);
    const float s0 = g2sel ? v0.w : v0.x;
    const float s1 = g2sel ? v1.w : v1.x;
    const float s2 = g2sel ? v2.w : v2.x;
    const float s3 = g2sel ? v3.w : v3.x;
    float sp1 = fmaxf(fmaxf(s0, s1), (h0 < 5)  ? s2 : NEG);   // rows [0,21)
    float sp2 = fmaxf(fmaxf(s2, s3), (h0 >= 3) ? s1 : NEG);   // rows [11,32)

    // ---- reduce over h0 (lane bits 3..5): xor8, xor16, permlane32 ----
#define RH(v) v = max_swz<SWZ_X8>(v); v = max_swz<SWZ_X16>(v); v = max_x32(v);
    RH(a0) RH(a1) RH(a2) RH(a3) RH(a4) RH(a5) RH(sp1) RH(sp2)
#undef RH
    // now lanes 0..7 hold per-column-group row-range maxes A[rr][g]

    // ---- per-lane region partials + reduce over g (lane bits 0..2) ----
#define RG3(v) v = max_swz<SWZ_X1>(v); v = max_swz<SWZ_X2>(v); v = max_swz<SWZ_X4>(v);

    float p0 = a0;                                      RG3(p0)    // full tile
    float p1 = (g <= 4) ? a1 : ((g == 5) ? sp1 : NEG);  RG3(p1)    // R[0,21) C[0,21)
    float p2 = (g >= 3) ? a1 : (g2sel ? sp1 : NEG);     RG3(p2)    // R[0,21) C[11,32)
    float p3 = (g <= 4) ? a2 : ((g == 5) ? sp2 : NEG);  RG3(p3)    // R[11,32) C[0,21)
    float p4 = (g >= 3) ? a2 : (g2sel ? sp2 : NEG);     RG3(p4)    // R[11,32) C[11,32)

    const bool c4 = (g >= 2) && (g < 6);                // cols [8,24) = groups 2..5
    // C[0,16): groups 0..3 -> xor1+xor2 gives lane0 = max(g0..g3)
    float p5  = max_swz<SWZ_X2>(max_swz<SWZ_X1>(a3));
    float p8  = max_swz<SWZ_X2>(max_swz<SWZ_X1>(a4));
    float p11 = max_swz<SWZ_X2>(max_swz<SWZ_X1>(a5));
    // C[8,24): masked full butterfly
    float p6  = c4 ? a3 : NEG;                          RG3(p6)
    float p9  = c4 ? a4 : NEG;                          RG3(p9)
    float p12 = c4 ? a5 : NEG;                          RG3(p12)
    // C[16,32): pre-swizzle xor4 (lane0 sees g4..g7), then xor1+xor2
    float p7  = max_swz<SWZ_X2>(max_swz<SWZ_X1>(swz<SWZ_X4>(a3)));
    float p10 = max_swz<SWZ_X2>(max_swz<SWZ_X1>(swz<SWZ_X4>(a4)));
    float p13 = max_swz<SWZ_X2>(max_swz<SWZ_X1>(swz<SWZ_X4>(a5)));
#undef RG3

    // packed per-tile record: vt[tile*16 + r] = p_r  (slots 14,15 padding)
    if (lane == 0) {
        float4* __restrict__ o = (float4*)(vt + ((long long)tile << 4));
        o[0] = make_float4(p0,  p1,  p2,  p3);
        o[1] = make_float4(p4,  p5,  p6,  p7);
        o[2] = make_float4(p8,  p9,  p10, p11);
        o[3] = make_float4(p12, p13, p13, p13);
    }

    // ---- last-block-per-b does the norm tail ----
    // Release: every thread fences its own stores, THEN barrier, THEN t0 counts.
    __threadfence();                         // device-scope release of vt stores
    __syncthreads();                         // all waves' stores+fences done
    __shared__ int isLast;
    const int b = blockIdx.x >> 7;           // 128 blocks per b
    if (threadIdx.x == 0)
        isLast = (atomicAdd(&cnt[b], 1) == 127) ? 1 : 0;
    __syncthreads();
    if (!isLast) return;
    __threadfence();                         // acquire: order reads after counter obs

    const int t = threadIdx.x;               // handles channels t and t+256
    float va[14], vb[14];
    {
        const float4* pA = (const float4*)(vt + (((long long)(b * C_ + t)) << 4));
        const float4* pB = (const float4*)(vt + (((long long)(b * C_ + t + 256)) << 4));
        float4 A0 = pA[0], A1 = pA[1], A2 = pA[2], A3 = pA[3];
        float4 B0 = pB[0], B1 = pB[1], B2 = pB[2], B3 = pB[3];
        va[0]=A0.x; va[1]=A0.y; va[2]=A0.z; va[3]=A0.w;
        va[4]=A1.x; va[5]=A1.y; va[6]=A1.z; va[7]=A1.w;
        va[8]=A2.x; va[9]=A2.y; va[10]=A2.z; va[11]=A2.w;
        va[12]=A3.x; va[13]=A3.y;
        vb[0]=B0.x; vb[1]=B0.y; vb[2]=B0.z; vb[3]=B0.w;
        vb[4]=B1.x; vb[5]=B1.y; vb[6]=B1.z; vb[7]=B1.w;
        vb[8]=B2.x; vb[9]=B2.y; vb[10]=B2.z; vb[11]=B2.w;
        vb[12]=B3.x; vb[13]=B3.y;
    }

    __shared__ float partial[14][4];
    __shared__ float inv[14];
    const int wid = t >> 6;
    const int ln  = t & 63;

#pragma unroll
    for (int r = 0; r < 14; ++r) {
        float s = va[r] * va[r] + vb[r] * vb[r];
#pragma unroll
        for (int off = 32; off > 0; off >>= 1)
            s += __shfl_down(s, off, 64);
        if (ln == 0) partial[r][wid] = s;
    }
    __syncthreads();

    if (t < 14) {
        float s = partial[t][0] + partial[t][1] + partial[t][2] + partial[t][3];
        inv[t] = 1.0f / (sqrtf(s) + 1e-6f);
    }
    __syncthreads();

    float accA = 2.0f * va[0] * inv[0];      // global pool == l=1 region, counted twice
    float accB = 2.0f * vb[0] * inv[0];
#pragma unroll
    for (int r = 1; r < 14; ++r) {
        accA += va[r] * inv[r];
        accB += vb[r] * inv[r];
    }
    out[b * C_ + t]       = accA;
    out[b * C_ + t + 256] = accB;
}

extern "C" void kernel_launch(void* const* d_in, const int* in_sizes, int n_in,
                              void* d_out, int out_size, void* d_ws, size_t ws_size,
                              hipStream_t stream) {
    const float* x  = (const float*)d_in[0];
    float* out      = (float*)d_out;
    float* vt       = (float*)d_ws;                        // 32768*16 floats = 2 MB
    int*   cnt      = (int*)((char*)d_ws + (BC * 16 * 4)); // 64 ints

    hipMemsetAsync(cnt, 0, B_ * sizeof(int), stream);
    rmac_fused_kernel<<<BC / 4, 256, 0, stream>>>(x, vt, cnt, out);  // 8192 blocks
}

// Round 6
// 236.765 us; speedup vs baseline: 5.5140x; 5.5140x over previous
//
#include <hip/hip_runtime.h>
#include <math.h>

// RMAC for x[64][512][32][32] fp32, L=3, OVR=0.4, EPS=1e-6.
// Regions for H=W=32 (14 distinct, global counted twice):
//   r0 : rows[0,32) cols[0,32)                       (weight 2)
//   r1-4 : rows{[0,21),[11,32)} x cols{[0,21),[11,32)}
//   r5-13: rows{[0,16),[8,24),[16,32)} x cols{[0,16),[8,24),[16,32)}
//
// v7: fused kernel; cross-block vt handoff via __hip_atomic_* AGENT-scope
// intrinsics (the rocPRIM decoupled-lookback pattern) instead of v6's
// hand-rolled inline asm (which core-dumped) and v4's __threadfence()
// (buffer_wbl2/buffer_inv per block -> 1182us).
//   - vt record words stored with __hip_atomic_store(RELAXED, AGENT):
//     device-coherent cache bits, no dirty per-XCD L2 line, no cache ops.
//   - release: s_waitcnt vmcnt(0) (stores retired at coherence point)
//     -> __syncthreads() -> t0 relaxed AGENT fetch_add on cnt[b].
//   - last block per b: relaxed AGENT loads (bypass local L2) -> norm tail.
// Pooling math identical to v2/v4 (verified absmax 0.0).

#define B_ 64
#define C_ 512
#define BC 32768            // B_*C_

template<int IMM>
__device__ __forceinline__ float max_swz(float x) {
    int y = __builtin_amdgcn_ds_swizzle(__float_as_int(x), IMM);
    return fmaxf(x, __int_as_float(y));
}
template<int IMM>
__device__ __forceinline__ float swz(float x) {
    return __int_as_float(__builtin_amdgcn_ds_swizzle(__float_as_int(x), IMM));
}
__device__ __forceinline__ float max_x32(float x) {
#if __has_builtin(__builtin_amdgcn_permlane32_swap)
    auto r = __builtin_amdgcn_permlane32_swap(__float_as_int(x), __float_as_int(x),
                                              false, false);
    return fmaxf(__int_as_float((int)r[0]), __int_as_float((int)r[1]));
#else
    return fmaxf(x, __shfl_xor(x, 32, 64));
#endif
}

// agent-scope (cross-XCD coherent) 8B packed store/load, relaxed ordering:
// compiler emits the correct gfx950 scope bits; no cache maintenance.
__device__ __forceinline__ void store2_agent(float* p, float a, float b) {
    unsigned long long v = ((unsigned long long)__float_as_uint(b) << 32)
                         | (unsigned long long)__float_as_uint(a);
    __hip_atomic_store((unsigned long long*)p, v,
                       __ATOMIC_RELAXED, __HIP_MEMORY_SCOPE_AGENT);
}
__device__ __forceinline__ float2 load2_agent(const float* p) {
    unsigned long long v =
        __hip_atomic_load((const unsigned long long*)p,
                          __ATOMIC_RELAXED, __HIP_MEMORY_SCOPE_AGENT);
    return make_float2(__uint_as_float((unsigned)(v & 0xffffffffu)),
                       __uint_as_float((unsigned)(v >> 32)));
}

#define SWZ_X1  0x041F
#define SWZ_X2  0x081F
#define SWZ_X4  0x101F
#define SWZ_X8  0x201F
#define SWZ_X16 0x401F

__global__ __launch_bounds__(256) void rmac_fused_kernel(const float* __restrict__ x,
                                                         float* __restrict__ vt,
                                                         int* __restrict__ cnt,
                                                         float* __restrict__ out) {
    const int lane = threadIdx.x & 63;
    const int tile = (blockIdx.x << 2) | (threadIdx.x >> 6);   // = b*C_ + c
    const float4* __restrict__ xv = (const float4*)(x + ((long long)tile << 10));

    // coalesced: 4 x (64 lanes x 16B) = the whole 4KB tile
    const float4 v0 = xv[lane];          // row h0,     cols 4g..4g+3
    const float4 v1 = xv[lane + 64];     // row h0+8
    const float4 v2 = xv[lane + 128];    // row h0+16
    const float4 v3 = xv[lane + 192];    // row h0+24

    const int h0 = lane >> 3;
    const int g  = lane & 7;
    const float NEG = -INFINITY;

    // per-row max over this lane's 4 columns
    const float gm0 = fmaxf(fmaxf(v0.x, v0.y), fmaxf(v0.z, v0.w));
    const float gm1 = fmaxf(fmaxf(v1.x, v1.y), fmaxf(v1.z, v1.w));
    const float gm2 = fmaxf(fmaxf(v2.x, v2.y), fmaxf(v2.z, v2.w));
    const float gm3 = fmaxf(fmaxf(v3.x, v3.y), fmaxf(v3.z, v3.w));

    // row-range maxes over the lane's rows {h0, h0+8, h0+16, h0+24}
    float a3 = fmaxf(gm0, gm1);                        // rows [0,16)
    float a5 = fmaxf(gm2, gm3);                        // rows [16,32)
    float a0 = fmaxf(a3, a5);                          // rows [0,32)
    float a4 = fmaxf(gm1, gm2);                        // rows [8,24)
    float a1 = fmaxf(a3, (h0 < 5)  ? gm2 : NEG);       // rows [0,21):  h0+16<21
    float a2 = fmaxf(a5, (h0 >= 3) ? gm1 : NEG);       // rows [11,32): h0+8>=11

    // special single columns: col 11 = (g2, j3); col 20 = (g5, j0)
    const bool g2sel = (g == 2);
    const float s0 = g2sel ? v0.w : v0.x;
    const float s1 = g2sel ? v1.w : v1.x;
    const float s2 = g2sel ? v2.w : v2.x;
    const float s3 = g2sel ? v3.w : v3.x;
    float sp1 = fmaxf(fmaxf(s0, s1), (h0 < 5)  ? s2 : NEG);   // rows [0,21)
    float sp2 = fmaxf(fmaxf(s2, s3), (h0 >= 3) ? s1 : NEG);   // rows [11,32)

    // ---- reduce over h0 (lane bits 3..5): xor8, xor16, permlane32 ----
#define RH(v) v = max_swz<SWZ_X8>(v); v = max_swz<SWZ_X16>(v); v = max_x32(v);
    RH(a0) RH(a1) RH(a2) RH(a3) RH(a4) RH(a5) RH(sp1) RH(sp2)
#undef RH
    // now lanes 0..7 hold per-column-group row-range maxes A[rr][g]

    // ---- per-lane region partials + reduce over g (lane bits 0..2) ----
#define RG3(v) v = max_swz<SWZ_X1>(v); v = max_swz<SWZ_X2>(v); v = max_swz<SWZ_X4>(v);

    float p0 = a0;                                      RG3(p0)    // full tile
    float p1 = (g <= 4) ? a1 : ((g == 5) ? sp1 : NEG);  RG3(p1)    // R[0,21) C[0,21)
    float p2 = (g >= 3) ? a1 : (g2sel ? sp1 : NEG);     RG3(p2)    // R[0,21) C[11,32)
    float p3 = (g <= 4) ? a2 : ((g == 5) ? sp2 : NEG);  RG3(p3)    // R[11,32) C[0,21)
    float p4 = (g >= 3) ? a2 : (g2sel ? sp2 : NEG);     RG3(p4)    // R[11,32) C[11,32)

    const bool c4 = (g >= 2) && (g < 6);                // cols [8,24) = groups 2..5
    // C[0,16): groups 0..3 -> xor1+xor2 gives lane0 = max(g0..g3)
    float p5  = max_swz<SWZ_X2>(max_swz<SWZ_X1>(a3));
    float p8  = max_swz<SWZ_X2>(max_swz<SWZ_X1>(a4));
    float p11 = max_swz<SWZ_X2>(max_swz<SWZ_X1>(a5));
    // C[8,24): masked full butterfly
    float p6  = c4 ? a3 : NEG;                          RG3(p6)
    float p9  = c4 ? a4 : NEG;                          RG3(p9)
    float p12 = c4 ? a5 : NEG;                          RG3(p12)
    // C[16,32): pre-swizzle xor4 (lane0 sees g4..g7), then xor1+xor2
    float p7  = max_swz<SWZ_X2>(max_swz<SWZ_X1>(swz<SWZ_X4>(a3)));
    float p10 = max_swz<SWZ_X2>(max_swz<SWZ_X1>(swz<SWZ_X4>(a4)));
    float p13 = max_swz<SWZ_X2>(max_swz<SWZ_X1>(swz<SWZ_X4>(a5)));
#undef RG3

    // packed per-tile record vt[tile*16 + 0..13], 7 x 8B agent-scope stores
    if (lane == 0) {
        float* o = vt + ((long long)tile << 4);
        store2_agent(o,      p0,  p1);
        store2_agent(o + 2,  p2,  p3);
        store2_agent(o + 4,  p4,  p5);
        store2_agent(o + 6,  p6,  p7);
        store2_agent(o + 8,  p8,  p9);
        store2_agent(o + 10, p10, p11);
        store2_agent(o + 12, p12, p13);
    }

    // ---- release ordering without cache maintenance ----
    // agent-scope stores are past the local L2 when vmcnt retires them;
    // drain, block-barrier, then count this block done (relaxed agent RMW).
    asm volatile("s_waitcnt vmcnt(0)" ::: "memory");
    __syncthreads();
    __shared__ int isLast;
    const int b = blockIdx.x >> 7;           // 128 blocks per b
    if (threadIdx.x == 0)
        isLast = (__hip_atomic_fetch_add(&cnt[b], 1, __ATOMIC_RELAXED,
                                         __HIP_MEMORY_SCOPE_AGENT) == 127) ? 1 : 0;
    __syncthreads();
    if (!isLast) return;

    // ---- last-block-per-b norm tail (agent loads bypass the local L2) ----
    const int t = threadIdx.x;               // handles channels t and t+256
    const float* pA = vt + (((long long)(b * C_ + t)) << 4);
    const float* pB = vt + (((long long)(b * C_ + t + 256)) << 4);
    float va[14], vb[14];
#pragma unroll
    for (int q = 0; q < 7; ++q) {
        float2 ra = load2_agent(pA + 2 * q);
        float2 rb = load2_agent(pB + 2 * q);
        va[2 * q] = ra.x; va[2 * q + 1] = ra.y;
        vb[2 * q] = rb.x; vb[2 * q + 1] = rb.y;
    }

    __shared__ float partial[14][4];
    __shared__ float inv[14];
    const int wid = t >> 6;
    const int ln  = t & 63;

#pragma unroll
    for (int r = 0; r < 14; ++r) {
        float s = va[r] * va[r] + vb[r] * vb[r];
#pragma unroll
        for (int off = 32; off > 0; off >>= 1)
            s += __shfl_down(s, off, 64);
        if (ln == 0) partial[r][wid] = s;
    }
    __syncthreads();

    if (t < 14) {
        float s = partial[t][0] + partial[t][1] + partial[t][2] + partial[t][3];
        inv[t] = 1.0f / (sqrtf(s) + 1e-6f);
    }
    __syncthreads();

    float accA = 2.0f * va[0] * inv[0];      // global pool == l=1 region, counted twice
    float accB = 2.0f * vb[0] * inv[0];
#pragma unroll
    for (int r = 1; r < 14; ++r) {
        accA += va[r] * inv[r];
        accB += vb[r] * inv[r];
    }
    out[b * C_ + t]       = accA;
    out[b * C_ + t + 256] = accB;
}

extern "C" void kernel_launch(void* const* d_in, const int* in_sizes, int n_in,
                              void* d_out, int out_size, void* d_ws, size_t ws_size,
                              hipStream_t stream) {
    const float* x  = (const float*)d_in[0];
    float* out      = (float*)d_out;
    float* vt       = (float*)d_ws;                        // 32768*16 floats = 2 MB
    int*   cnt      = (int*)((char*)d_ws + (BC * 16 * 4)); // 64 ints

    (void)hipMemsetAsync(cnt, 0, B_ * sizeof(int), stream);
    rmac_fused_kernel<<<BC / 4, 256, 0, stream>>>(x, vt, cnt, out);  // 8192 blocks
}

// Round 7
// 189.937 us; speedup vs baseline: 6.8735x; 1.2465x over previous
//
#include <hip/hip_runtime.h>
#include <math.h>

// RMAC for x[64][512][32][32] fp32, L=3, OVR=0.4, EPS=1e-6.
// Regions for H=W=32 (14 distinct, global counted twice):
//   r0 : rows[0,32) cols[0,32)                       (weight 2)
//   r1-4 : rows{[0,21),[11,32)} x cols{[0,21),[11,32)}
//   r5-13: rows{[0,16),[8,24),[16,32)} x cols{[0,16),[8,24),[16,32)}
//
// v8: back to the proven TWO-KERNEL structure (fusion abandoned: v7 counters
// showed the cross-block agent/sc1 handoff costs ~70us of MALL round-trips,
// far more than the ~10us launch it saves).
// Pool kernel changes vs v2:
//   - ALL reduction steps moved from ds_swizzle (LDS pipe, ~7K ops/CU
//     serializing against the 21us HBM floor) to VALU DPP/permlane:
//       xor1 -> quad_perm[1,0,3,2], xor2 -> quad_perm[2,3,0,1],
//       xor4 -> row_ror:4 (valid: bits 0,1 and 3..5 uniform when applied),
//       xor8 -> row_ror:8, xor16 -> v_permlane16_swap, xor32 -> v_permlane32_swap.
//     Pool kernel now has ZERO LDS instructions.
//   - packed vt[tile][16] record, 4x float4 cached stores (one 64B line).
// Norm kernel: 64 blocks x 512 threads, 4x coalesced float4 loads per channel.
// Producer->consumer coherence via kernel boundary (same-stream dispatch
// ordering), exactly as the passing rounds 0/1 relied on.

#define B_ 64
#define C_ 512
#define BC 32768            // B_*C_

// ---- VALU-pipe cross-lane max helpers (no LDS pipe) ----
__device__ __forceinline__ float dpp_shuf(float x, int ctrl_unused) { return x; }

template<int CTRL>
__device__ __forceinline__ float dppmv(float x) {     // pure DPP shuffle
    return __int_as_float(__builtin_amdgcn_update_dpp(
        __float_as_int(x), __float_as_int(x), CTRL, 0xF, 0xF, false));
}
template<int CTRL>
__device__ __forceinline__ float max_dpp(float x) {   // x = max(x, dpp(x))
    return fmaxf(x, dppmv<CTRL>(x));
}
#define DPP_XOR1 0xB1   // quad_perm [1,0,3,2]
#define DPP_XOR2 0x4E   // quad_perm [2,3,0,1]
#define DPP_ROR4 0x124  // row_ror:4
#define DPP_ROR8 0x128  // row_ror:8

__device__ __forceinline__ float max_x16(float x) {
#if __has_builtin(__builtin_amdgcn_permlane16_swap)
    auto r = __builtin_amdgcn_permlane16_swap(__float_as_int(x), __float_as_int(x),
                                              false, false);
    return fmaxf(__int_as_float((int)r[0]), __int_as_float((int)r[1]));
#else
    return fmaxf(x, __shfl_xor(x, 16, 64));
#endif
}
__device__ __forceinline__ float max_x32(float x) {
#if __has_builtin(__builtin_amdgcn_permlane32_swap)
    auto r = __builtin_amdgcn_permlane32_swap(__float_as_int(x), __float_as_int(x),
                                              false, false);
    return fmaxf(__int_as_float((int)r[0]), __int_as_float((int)r[1]));
#else
    return fmaxf(x, __shfl_xor(x, 32, 64));
#endif
}

__global__ __launch_bounds__(256) void rmac_pool_kernel(const float* __restrict__ x,
                                                        float* __restrict__ vt) {
    const int lane = threadIdx.x & 63;
    const int tile = (blockIdx.x << 2) | (threadIdx.x >> 6);   // = b*C_ + c
    const float4* __restrict__ xv = (const float4*)(x + ((long long)tile << 10));

    // coalesced: 4 x (64 lanes x 16B) = the whole 4KB tile
    const float4 v0 = xv[lane];          // row h0,     cols 4g..4g+3
    const float4 v1 = xv[lane + 64];     // row h0+8
    const float4 v2 = xv[lane + 128];    // row h0+16
    const float4 v3 = xv[lane + 192];    // row h0+24

    const int h0 = lane >> 3;
    const int g  = lane & 7;
    const float NEG = -INFINITY;

    // per-row max over this lane's 4 columns
    const float gm0 = fmaxf(fmaxf(v0.x, v0.y), fmaxf(v0.z, v0.w));
    const float gm1 = fmaxf(fmaxf(v1.x, v1.y), fmaxf(v1.z, v1.w));
    const float gm2 = fmaxf(fmaxf(v2.x, v2.y), fmaxf(v2.z, v2.w));
    const float gm3 = fmaxf(fmaxf(v3.x, v3.y), fmaxf(v3.z, v3.w));

    // row-range maxes over the lane's rows {h0, h0+8, h0+16, h0+24}
    float a3 = fmaxf(gm0, gm1);                        // rows [0,16)
    float a5 = fmaxf(gm2, gm3);                        // rows [16,32)
    float a0 = fmaxf(a3, a5);                          // rows [0,32)
    float a4 = fmaxf(gm1, gm2);                        // rows [8,24)
    float a1 = fmaxf(a3, (h0 < 5)  ? gm2 : NEG);       // rows [0,21):  h0+16<21
    float a2 = fmaxf(a5, (h0 >= 3) ? gm1 : NEG);       // rows [11,32): h0+8>=11

    // special single columns: col 11 = (g2, j3); col 20 = (g5, j0)
    const bool g2sel = (g == 2);
    const float s0 = g2sel ? v0.w : v0.x;
    const float s1 = g2sel ? v1.w : v1.x;
    const float s2 = g2sel ? v2.w : v2.x;
    const float s3 = g2sel ? v3.w : v3.x;
    float sp1 = fmaxf(fmaxf(s0, s1), (h0 < 5)  ? s2 : NEG);   // rows [0,21)
    float sp2 = fmaxf(fmaxf(s2, s3), (h0 >= 3) ? s1 : NEG);   // rows [11,32)

    // ---- reduce over h0 (lane bits 3..5): ror8 + permlane16 + permlane32 ----
    // (row_ror:8 pairs lane i with i^8 within each 16-row; bits 4,5 via
    //  permlane16/32_swap. All VALU pipe.)
#define RH(v) v = max_dpp<DPP_ROR8>(v); v = max_x16(v); v = max_x32(v);
    RH(a0) RH(a1) RH(a2) RH(a3) RH(a4) RH(a5) RH(sp1) RH(sp2)
#undef RH
    // now every 8-lane group holds per-column-group row-range maxes A[rr][g]

    // ---- per-lane region partials + reduce over g (lane bits 0..2) ----
    // xor1/xor2 via quad_perm; bit2 via row_ror:4 (valid: after xor1,xor2 and
    // the h-reduction, lane value within a 16-row depends only on bit2, and
    // ror:4 always flips bit2). Only lane 0's final value is stored.
#define RG3(v) v = max_dpp<DPP_XOR1>(v); v = max_dpp<DPP_XOR2>(v); v = max_dpp<DPP_ROR4>(v);

    float p0 = a0;                                      RG3(p0)    // full tile
    float p1 = (g <= 4) ? a1 : ((g == 5) ? sp1 : NEG);  RG3(p1)    // R[0,21) C[0,21)
    float p2 = (g >= 3) ? a1 : (g2sel ? sp1 : NEG);     RG3(p2)    // R[0,21) C[11,32)
    float p3 = (g <= 4) ? a2 : ((g == 5) ? sp2 : NEG);  RG3(p3)    // R[11,32) C[0,21)
    float p4 = (g >= 3) ? a2 : (g2sel ? sp2 : NEG);     RG3(p4)    // R[11,32) C[11,32)

    const bool c4 = (g >= 2) && (g < 6);                // cols [8,24) = groups 2..5
    // C[0,16): groups 0..3 -> xor1+xor2 gives lane0 = max(g0..g3)
    float p5  = max_dpp<DPP_XOR2>(max_dpp<DPP_XOR1>(a3));
    float p8  = max_dpp<DPP_XOR2>(max_dpp<DPP_XOR1>(a4));
    float p11 = max_dpp<DPP_XOR2>(max_dpp<DPP_XOR1>(a5));
    // C[8,24): masked full butterfly
    float p6  = c4 ? a3 : NEG;                          RG3(p6)
    float p9  = c4 ? a4 : NEG;                          RG3(p9)
    float p12 = c4 ? a5 : NEG;                          RG3(p12)
    // C[16,32): pre-shuffle ror4 (lane0 sees g4), then xor1+xor2 -> {g4..g7}
    float p7  = max_dpp<DPP_XOR2>(max_dpp<DPP_XOR1>(dppmv<DPP_ROR4>(a3)));
    float p10 = max_dpp<DPP_XOR2>(max_dpp<DPP_XOR1>(dppmv<DPP_ROR4>(a4)));
    float p13 = max_dpp<DPP_XOR2>(max_dpp<DPP_XOR1>(dppmv<DPP_ROR4>(a5)));
#undef RG3

    // packed per-tile record: vt[tile*16 + r] (slots 14,15 padding), one 64B line
    if (lane == 0) {
        float4* __restrict__ o = (float4*)(vt + ((long long)tile << 4));
        o[0] = make_float4(p0,  p1,  p2,  p3);
        o[1] = make_float4(p4,  p5,  p6,  p7);
        o[2] = make_float4(p8,  p9,  p10, p11);
        o[3] = make_float4(p12, p13, p13, p13);
    }
}

__global__ __launch_bounds__(512) void rmac_norm_kernel(const float* __restrict__ vt,
                                                        float* __restrict__ out) {
    const int b = blockIdx.x;
    const int c = threadIdx.x;

    // packed record: 4 coalesced float4 loads (consecutive threads 64B apart)
    const float4* __restrict__ p = (const float4*)(vt + (((long long)(b * C_ + c)) << 4));
    const float4 q0 = p[0], q1 = p[1], q2 = p[2], q3 = p[3];
    float v[14];
    v[0]=q0.x; v[1]=q0.y; v[2]=q0.z; v[3]=q0.w;
    v[4]=q1.x; v[5]=q1.y; v[6]=q1.z; v[7]=q1.w;
    v[8]=q2.x; v[9]=q2.y; v[10]=q2.z; v[11]=q2.w;
    v[12]=q3.x; v[13]=q3.y;

    __shared__ float partial[14][8];
    __shared__ float inv[14];
    const int wid  = c >> 6;
    const int lane = c & 63;

#pragma unroll
    for (int r = 0; r < 14; ++r) {
        float s = v[r] * v[r];
#pragma unroll
        for (int off = 32; off > 0; off >>= 1)
            s += __shfl_down(s, off, 64);
        if (lane == 0) partial[r][wid] = s;
    }
    __syncthreads();

    if (c < 14) {
        float s = 0.f;
#pragma unroll
        for (int wI = 0; wI < 8; ++wI) s += partial[c][wI];
        inv[c] = 1.0f / (sqrtf(s) + 1e-6f);
    }
    __syncthreads();

    float acc = 2.0f * v[0] * inv[0];   // global pool == l=1 region, counted twice
#pragma unroll
    for (int r = 1; r < 14; ++r) acc += v[r] * inv[r];
    out[b * C_ + c] = acc;
}

extern "C" void kernel_launch(void* const* d_in, const int* in_sizes, int n_in,
                              void* d_out, int out_size, void* d_ws, size_t ws_size,
                              hipStream_t stream) {
    const float* x  = (const float*)d_in[0];
    float* out      = (float*)d_out;
    float* vt       = (float*)d_ws;   // 32768*16 floats = 2 MB

    rmac_pool_kernel<<<BC / 4, 256, 0, stream>>>(x, vt);    // 8192 blocks, 1 wave/tile
    rmac_norm_kernel<<<B_, 512, 0, stream>>>(vt, out);      // 64 blocks
}